// Round 13
// baseline (75.589 us; speedup 1.0000x reference)
//
#include <hip/hip_runtime.h>
#include <hip/hip_bf16.h>

#define EPS 1e-5f

// dims: feat (2,128,128,128) f32 NCHW, guide (2,3,256,256) f32 NCHW,
// out (2,128,256,256) f32 NCHW. E=32, K=3, k2=9. H2=W2=256.
// x1,x2 bf16 NHWC (2,256,256,32) in d_out; fs bf16 NHWC, packed weights,
// stats partials in d_ws. 3 launches; stats fused into producers (LDS tree),
// BN-ab reduced inline by consumers.

typedef unsigned short ushort_t;
typedef __attribute__((ext_vector_type(8))) short short8v;   // 8 bf16 = 4 VGPR
typedef __attribute__((ext_vector_type(4))) float f32x4;

__device__ __forceinline__ int swz(int b) { return b ^ (((b >> 7) & 7) << 4); }
__device__ __forceinline__ float bf2f(ushort_t u) {
    unsigned int t = ((unsigned int)u) << 16;
    return __builtin_bit_cast(float, t);
}
__device__ __forceinline__ ushort_t f2bf(float f) {   // RNE via HW cvt
    __hip_bfloat16 h = (__hip_bfloat16)f;
    return __builtin_bit_cast(ushort_t, h);
}

// inline BN-coefficient reduction: part[512][64] -> red[320..384) = {a[32],b[32]}
__device__ __forceinline__ void ab_inline(
    const float* __restrict__ part, const float* __restrict__ gamma,
    const float* __restrict__ beta, float* red, int tid)
{
    int col = tid & 63, quart = tid >> 6;
    float s = 0.f;
    const float* p = part + (size_t)(quart * 128) * 64 + col;
#pragma unroll 8
    for (int bq = 0; bq < 128; ++bq) s += p[(size_t)bq * 64];
    red[quart * 64 + col] = s;
    __syncthreads();
    if (tid < 64)
        red[256 + tid] = red[tid] + red[64 + tid] + red[128 + tid] + red[192 + tid];
    __syncthreads();
    if (tid < 32) {
        float S  = red[256 + (tid >> 1) * 4 + (tid & 1) * 2];
        float SS = red[256 + (tid >> 1) * 4 + (tid & 1) * 2 + 1];
        const float n = 131072.f;
        float mean = S / n;
        float var = SS / n - mean * mean;
        float a = gamma[tid] * rsqrtf(var + EPS);
        red[320 + tid] = a;
        red[352 + tid] = beta[tid] - mean * a;
    }
    __syncthreads();
}

// ---- phase 1: conv1+stats | proj (local pw pack) | weight prep ----------
// grid: [0,512) conv1 | [512,768) proj | [768,876) prep
__global__ __launch_bounds__(256) void k_phase1(
    const float* __restrict__ guide, const float* __restrict__ w1,
    const float* __restrict__ w2, const float* __restrict__ kw1,
    const float* __restrict__ pw, const float* __restrict__ feat,
    ushort_t* __restrict__ x1, ushort_t* __restrict__ fs,
    ushort_t* __restrict__ wpk, float* __restrict__ part1)
{
    __shared__ __align__(16) char lds[40960];
    int tid = threadIdx.x;
    int blk = blockIdx.x;

    if (blk < 512) {
        // ---- conv1: guide 3->32, LDS-tiled, out bf16 NHWC + stats ----
        float* smu = (float*)lds;                    // [0, 4104)
        int b = blk >> 8;
        int tile = blk & 255;
        int ty0 = (tile >> 4) << 4, tx0 = (tile & 15) << 4;

        for (int i = tid; i < 972; i += 256) {
            int c = i / 324;
            int rem = i - c * 324;
            int r = rem / 18, cl = rem - r * 18;
            int yy = ty0 + r - 1, xx = tx0 + cl - 1;
            float v = 0.f;
            if (yy >= 0 && yy < 256 && xx >= 0 && xx < 256)
                v = guide[((b * 3 + c) * 256 + yy) * 256 + xx];
            smu[c * 342 + r * 19 + cl] = v;
        }
        __syncthreads();

        int r = tid >> 4, cl = tid & 15;
        float t[27];
#pragma unroll
        for (int c = 0; c < 3; ++c)
#pragma unroll
            for (int ky = 0; ky < 3; ++ky)
#pragma unroll
                for (int kx = 0; kx < 3; ++kx)
                    t[c * 9 + ky * 3 + kx] = smu[c * 342 + (r + ky) * 19 + cl + kx];
        int y = ty0 + r, x = tx0 + cl;
        float* sdump = (float*)(lds + 4224);         // [256 px][33] f32
        ushort_t pk[32];
#pragma unroll 4
        for (int e = 0; e < 32; ++e) {
            float acc = 0.f;
#pragma unroll
            for (int k = 0; k < 27; ++k)
                acc += t[k] * w1[e * 27 + k];
            pk[e] = f2bf(acc);
            sdump[tid * 33 + e] = bf2f(pk[e]);
        }
        ushort_t* dst = x1 + ((size_t)(b * 65536 + y * 256 + x)) * 32;
#pragma unroll
        for (int h = 0; h < 4; ++h)
            *(uint4*)(dst + h * 8) = *(uint4*)(pk + h * 8);

        // ---- per-block partial stats via LDS tree ----
        __syncthreads();
        {
            int ch = tid & 31, seg = tid >> 5;       // 8 segs x 32 px
            float s = 0.f, q = 0.f;
#pragma unroll 8
            for (int i = 0; i < 32; ++i) {
                float v = sdump[(seg * 32 + i) * 33 + ch];
                s += v; q += v * v;
            }
            float* segbuf = (float*)(lds + 38016);   // [256][2] f32
            segbuf[(seg * 32 + ch) * 2 + 0] = s;
            segbuf[(seg * 32 + ch) * 2 + 1] = q;
            __syncthreads();
            if (tid < 64) {
                int c = tid >> 1, isq = tid & 1;
                float tt = 0.f;
#pragma unroll
                for (int g = 0; g < 8; ++g)
                    tt += segbuf[(g * 32 + c) * 2 + isq];
                int col = (c >> 1) * 4 + (c & 1) * 2 + isq;
                part1[(size_t)blk * 64 + col] = tt;
            }
        }
    } else if (blk < 768) {
        // ---- proj: 1x1 conv 128->32 MFMA; pw packed into LDS locally ----
        int row = blk - 512;              // 0..255
        int b = row >> 7, yl = row & 127;
        ushort_t* pwl = (ushort_t*)(lds + 32768);     // 4096 bf16 B-frags

        for (int i = tid; i < 4096; i += 256) {
            int j = i & 7, l = (i >> 3) & 63, nt = (i >> 9) & 1, ks = i >> 10;
            int e = nt * 16 + (l & 15);
            int c = ks * 32 + (l >> 4) * 8 + j;
            pwl[i] = f2bf(pw[e * 128 + c]);
        }
        int x = tid & 127, cg = tid >> 7;
        const float* fb = feat + ((size_t)b << 21) + yl * 128 + x;
#pragma unroll
        for (int p = 0; p < 8; ++p) {
            int c0 = p * 16 + cg * 8;
            ushort_t pk[8];
#pragma unroll
            for (int j = 0; j < 8; ++j)
                pk[j] = f2bf(fb[(size_t)(c0 + j) << 14]);
            *(uint4*)(lds + swz(x * 256 + c0 * 2)) = *(uint4*)pk;
        }
        __syncthreads();

        int w = tid >> 6, l = tid & 63, lm = l & 15, lg = l >> 4;
        int px0 = w * 32;
        f32x4 acc[2][2] = {};
        const short8v* gB = (const short8v*)pwl;
#pragma unroll
        for (int ks = 0; ks < 4; ++ks) {
            short8v B0 = gB[(ks * 2 + 0) * 64 + l];
            short8v B1 = gB[(ks * 2 + 1) * 64 + l];
#pragma unroll
            for (int m = 0; m < 2; ++m) {
                short8v A = *(const short8v*)(
                    lds + swz((px0 + m * 16 + lm) * 256 + ks * 64 + lg * 16));
                acc[m][0] = __builtin_amdgcn_mfma_f32_16x16x32_bf16(A, B0, acc[m][0], 0, 0, 0);
                acc[m][1] = __builtin_amdgcn_mfma_f32_16x16x32_bf16(A, B1, acc[m][1], 0, 0, 0);
            }
        }
        __syncthreads();
#pragma unroll
        for (int m = 0; m < 2; ++m)
#pragma unroll
            for (int nt = 0; nt < 2; ++nt)
#pragma unroll
                for (int rg = 0; rg < 4; ++rg) {
                    int px = px0 + m * 16 + lg * 4 + rg;
                    int e = nt * 16 + lm;
                    *(ushort_t*)(lds + swz(px * 64 + e * 2)) =
                        f2bf(fmaxf(acc[m][nt][rg], 0.f));
                }
        __syncthreads();
        if (tid < 128) {
            ushort_t* dst = fs + ((size_t)(b * 16384 + yl * 128 + tid)) * 32;
#pragma unroll
            for (int h = 0; h < 4; ++h)
                *(uint4*)(dst + h * 8) = *(uint4*)(lds + swz(tid * 64 + h * 16));
        }
    } else {
        // ---- weight prep: w2 | kw1 into B-fragment order, bf16 ----
        int i = (blk - 768) * 256 + tid;     // 0..27647
        if (i < 9216) {
            int j = i & 7, l = (i >> 3) & 63, nt = (i >> 9) & 1, t = i >> 10;
            int e = nt * 16 + (l & 15);
            int k = (l >> 4) * 8 + j;
            wpk[i] = f2bf(w2[(e * 32 + k) * 9 + t]);
        } else {
            int i2 = i - 9216;
            int j = i2 & 7, l = (i2 >> 3) & 63, nt = (i2 >> 9) & 1;
            int kk = (i2 >> 10) & 1, t = i2 >> 11;
            int e = nt * 16 + (l & 15);
            int k = kk * 32 + (l >> 4) * 8 + j;
            wpk[i] = f2bf(kw1[(e * 64 + k) * 9 + t]);
        }
    }
}

// ---- conv2: bnrelu(x1) 32->32, bf16 MFMA; ab inline; stats fused -------
__global__ __launch_bounds__(256) void k_conv2(
    const ushort_t* __restrict__ x1, const float* __restrict__ part1,
    const float* __restrict__ gamma, const float* __restrict__ beta,
    const ushort_t* __restrict__ w2pk, ushort_t* __restrict__ x2,
    float* __restrict__ part2)
{
    __shared__ __align__(16) char lds[22784];    // 20736 staging + 2048 red/seg
    float* red = (float*)(lds + 20736);
    int tid = threadIdx.x;
    ab_inline(part1, gamma, beta, red, tid);
    const float* ab1 = red + 320;

    int b = blockIdx.x >> 8, tile = blockIdx.x & 255;
    int ty0 = (tile >> 4) << 4, tx0 = (tile & 15) << 4;

    for (int i = tid; i < 1296; i += 256) {
        int px = i >> 2, c8 = i & 3;
        int r = px / 18, cl = px - r * 18;
        int yy = ty0 + r - 1, xx = tx0 + cl - 1;
        ushort_t pk[8];
        if (yy >= 0 && yy < 256 && xx >= 0 && xx < 256) {
            const ushort_t* src = x1 + ((size_t)(b * 65536 + yy * 256 + xx)) * 32 + c8 * 8;
            uint4 raw = *(const uint4*)src;
            const ushort_t* rs = (const ushort_t*)&raw;
#pragma unroll
            for (int j = 0; j < 8; ++j) {
                int c = c8 * 8 + j;
                pk[j] = f2bf(fmaxf(ab1[c] * bf2f(rs[j]) + ab1[32 + c], 0.f));
            }
        } else {
#pragma unroll
            for (int j = 0; j < 8; ++j) pk[j] = 0;
        }
        *(uint4*)(lds + swz(px * 64 + c8 * 16)) = *(uint4*)pk;
    }
    __syncthreads();

    int w = tid >> 6, l = tid & 63, lm = l & 15, lg = l >> 4;
    f32x4 acc[4][2] = {};
    const short8v* gB = (const short8v*)w2pk;
#pragma unroll
    for (int t = 0; t < 9; ++t) {
        int ky = t / 3, kx = t % 3;
        short8v B0 = gB[(t * 2 + 0) * 64 + l];
        short8v B1 = gB[(t * 2 + 1) * 64 + l];
#pragma unroll
        for (int m = 0; m < 4; ++m) {
            int px = (w * 4 + m + ky) * 18 + lm + kx;
            short8v A = *(const short8v*)(lds + swz(px * 64 + lg * 16));
            acc[m][0] = __builtin_amdgcn_mfma_f32_16x16x32_bf16(A, B0, acc[m][0], 0, 0, 0);
            acc[m][1] = __builtin_amdgcn_mfma_f32_16x16x32_bf16(A, B1, acc[m][1], 0, 0, 0);
        }
    }
    __syncthreads();
#pragma unroll
    for (int m = 0; m < 4; ++m)
#pragma unroll
        for (int nt = 0; nt < 2; ++nt)
#pragma unroll
            for (int rg = 0; rg < 4; ++rg) {
                int px = (w * 4 + m) * 16 + lg * 4 + rg;
                int e = nt * 16 + lm;
                *(ushort_t*)(lds + swz(px * 64 + e * 2)) = f2bf(acc[m][nt][rg]);
            }
    __syncthreads();
    {
        int px = tid, r = px >> 4, cl = px & 15;
        int yy = ty0 + r, xx = tx0 + cl;
        ushort_t* dst = x2 + ((size_t)(b * 65536 + yy * 256 + xx)) * 32;
#pragma unroll
        for (int h = 0; h < 4; ++h)
            *(uint4*)(dst + h * 8) = *(uint4*)(lds + swz(px * 64 + h * 16));
    }

    // ---- fused stats of x2 tile straight from the bf16 LDS dump ----
    {
        int ch = tid & 31, seg = tid >> 5;
        float s = 0.f, q = 0.f;
#pragma unroll 8
        for (int i = 0; i < 32; ++i) {
            int px = seg * 32 + i;
            float v = bf2f(*(const ushort_t*)(lds + swz(px * 64 + ch * 2)));
            s += v; q += v * v;
        }
        float* segbuf = (float*)(lds + 20736);    // red region dead now
        __syncthreads();                          // ensure x2 reads done
        segbuf[(seg * 32 + ch) * 2 + 0] = s;
        segbuf[(seg * 32 + ch) * 2 + 1] = q;
        __syncthreads();
        if (tid < 64) {
            int c = tid >> 1, isq = tid & 1;
            float tt = 0.f;
#pragma unroll
            for (int g = 0; g < 8; ++g)
                tt += segbuf[(g * 32 + c) * 2 + isq];
            int col = (c >> 1) * 4 + (c & 1) * 2 + isq;
            part2[(size_t)blockIdx.x * 64 + col] = tt;
        }
    }
}

// ---- fused tail: conv3x3 64->32 (MFMA) + head + softmax + reassembly ---
// Tile = 16w x 8h highres; 1024 blocks; XCD-paired tile swizzle.
__global__ __launch_bounds__(256) void k_tail(
    const ushort_t* __restrict__ x2, const float* __restrict__ part2,
    const float* __restrict__ gamma, const float* __restrict__ beta,
    const ushort_t* __restrict__ fs, const ushort_t* __restrict__ kw1pk,
    const float* __restrict__ kw2, const float* __restrict__ kb2,
    const float* __restrict__ feat, float* __restrict__ out)
{
    // [0,33600): comb (23040B) -> head dump (16KB) -> lf2 [60 pos][140] f32
    // [33600,35648): red scratch (1536B, dies) then coef 128 px * 4 f32
    __shared__ __align__(16) char lds[35648];
    int tid = threadIdx.x;

    // XCD-paired swizzle: adjacent-x tiles -> same XCD, adjacent dispatch.
    int p = blockIdx.x;                    // 1024
    int xcd = p & 7, q = p >> 3;
    int g = xcd * 64 + (q >> 1);           // tile-pair id, 512 total
    int b = g >> 8;
    int rem = g & 255;
    int ty0 = (rem >> 3) << 3;
    int tx0 = (((rem & 7) << 1) | (q & 1)) << 4;

    // ---- phase A part 1: stage fs chunks (no ab needed) + issue x2 raws
    for (int i = tid; i < 720; i += 256) {     // fs: 180 px * 4 chunks
        int px = i >> 2, c4 = i & 3;
        int r = px / 18, cl = px - r * 18;
        int yy = ty0 + r - 1, xx = tx0 + cl - 1;
        uint4 v = { 0, 0, 0, 0 };
        if (yy >= 0 && yy < 256 && xx >= 0 && xx < 256)
            v = *(const uint4*)(fs + ((size_t)(b * 16384 + (yy >> 1) * 128 + (xx >> 1))) * 32 + c4 * 8);
        *(uint4*)(lds + swz(px * 128 + (c4 + 4) * 16)) = v;
    }
    uint4 raw[3]; bool val[3]; int offs[3];
#pragma unroll
    for (int s = 0; s < 3; ++s) {              // x2: 180 px * 4 chunks
        int i = tid + s * 256;
        int px = i >> 2, c4 = i & 3;
        int r = px / 18, cl = px - r * 18;
        int yy = ty0 + r - 1, xx = tx0 + cl - 1;
        bool inb = (i < 720) && yy >= 0 && yy < 256 && xx >= 0 && xx < 256;
        val[s] = inb;
        offs[s] = swz(px * 128 + c4 * 16);
        uint4 v = { 0, 0, 0, 0 };
        if (inb)
            v = *(const uint4*)(x2 + ((size_t)(b * 65536 + yy * 256 + xx)) * 32 + c4 * 8);
        raw[s] = v;
        if (i < 720 && !inb) *(uint4*)(lds + offs[s]) = v;
    }

    float* redz = (float*)(lds + 33600);
    ab_inline(part2, gamma, beta, redz, tid);  // x2 loads in flight above
    const float* ab2 = redz + 320;

    // ---- phase A part 2: bnrelu the raw x2 regs -> LDS ----
#pragma unroll
    for (int s = 0; s < 3; ++s) {
        if (val[s]) {
            int c0 = ((tid + s * 256) & 3) * 8;
            const ushort_t* rs = (const ushort_t*)&raw[s];
            ushort_t pk[8];
#pragma unroll
            for (int j = 0; j < 8; ++j)
                pk[j] = f2bf(fmaxf(ab2[c0 + j] * bf2f(rs[j]) + ab2[32 + c0 + j], 0.f));
            *(uint4*)(lds + offs[s]) = *(uint4*)pk;
        }
    }
    __syncthreads();

    // ---- MFMA: 8 m-tiles (one output row each), 4 waves x 2 mt ---------
    int w = tid >> 6, l = tid & 63, lm = l & 15, lg = l >> 4;
    f32x4 acc[2][2] = {};
    {
        const short8v* gB = (const short8v*)kw1pk;
#pragma unroll
        for (int t = 0; t < 9; ++t) {
            int ky = t / 3, kx = t % 3;
#pragma unroll
            for (int kk = 0; kk < 2; ++kk) {
                short8v B0 = gB[(t * 4 + kk * 2 + 0) * 64 + l];
                short8v B1 = gB[(t * 4 + kk * 2 + 1) * 64 + l];
#pragma unroll
                for (int m = 0; m < 2; ++m) {
                    int mt = w * 2 + m;
                    int px = (mt + ky) * 18 + lm + kx;
                    short8v A = *(const short8v*)(lds + swz(px * 128 + kk * 64 + lg * 16));
                    acc[m][0] = __builtin_amdgcn_mfma_f32_16x16x32_bf16(A, B0, acc[m][0], 0, 0, 0);
                    acc[m][1] = __builtin_amdgcn_mfma_f32_16x16x32_bf16(A, B1, acc[m][1], 0, 0, 0);
                }
            }
        }
    }
    __syncthreads();
#pragma unroll
    for (int m = 0; m < 2; ++m)
#pragma unroll
        for (int nt = 0; nt < 2; ++nt)
#pragma unroll
            for (int rg = 0; rg < 4; ++rg) {
                int px = (w * 2 + m) * 16 + lg * 4 + rg;
                int e = nt * 16 + lm;
                *(float*)(lds + swz(px * 128 + e * 4)) = acc[m][nt][rg];
            }
    __syncthreads();

    // ---- head (tid<128): ReLU -> 1x1 -> softmax -> collapsed coeffs ----
    float* coef = (float*)(lds + 33600);       // red region dead
    if (tid < 128) {
        int px = tid;
        float v[32];
#pragma unroll
        for (int h = 0; h < 8; ++h) {
            float4 qd = *(const float4*)(lds + swz(px * 128 + h * 16));
            v[h * 4 + 0] = qd.x; v[h * 4 + 1] = qd.y; v[h * 4 + 2] = qd.z; v[h * 4 + 3] = qd.w;
        }
        float z[9];
#pragma unroll
        for (int i = 0; i < 9; ++i) z[i] = kb2[i];
#pragma unroll
        for (int e = 0; e < 32; ++e) {
            float ae = fmaxf(v[e], 0.f);
#pragma unroll
            for (int i = 0; i < 9; ++i)
                z[i] += ae * kw2[i * 32 + e];
        }
        float m = z[0];
#pragma unroll
        for (int i = 1; i < 9; ++i) m = fmaxf(m, z[i]);
        float sum = 0.f;
#pragma unroll
        for (int i = 0; i < 9; ++i) { z[i] = expf(z[i] - m); sum += z[i]; }
        float inv = 1.f / sum;
#pragma unroll
        for (int i = 0; i < 9; ++i) z[i] *= inv;
        // parity-collapse: 9 taps -> {co00,co01,co10,co11}
        int r = px >> 4, cl = px & 15;
        int ry = r & 1, rx = cl & 1;
        float zr0[3], zr1[3];
#pragma unroll
        for (int dx = 0; dx < 3; ++dx) {
            if (ry == 0) { zr0[dx] = z[dx];            zr1[dx] = z[3 + dx] + z[6 + dx]; }
            else         { zr0[dx] = z[dx] + z[3 + dx]; zr1[dx] = z[6 + dx]; }
        }
        float4 cf;
        if (rx == 0) { cf.x = zr0[0];           cf.y = zr0[1] + zr0[2];
                       cf.z = zr1[0];           cf.w = zr1[1] + zr1[2]; }
        else         { cf.x = zr0[0] + zr0[1];  cf.y = zr0[2];
                       cf.z = zr1[0] + zr1[1];  cf.w = zr1[2]; }
        *(float4*)(coef + px * 4) = cf;
    }
    __syncthreads();

    // ---- phase B: stage feat fp32 pos-major [60 pos][140 ch-pad] -------
    float* lf2 = (float*)lds;
    {
        int ty0l = ty0 >> 1, tx0l = tx0 >> 1;
        for (int i = tid; i < 3072; i += 256) {     // 128 ch * 6 rows * 4 q
            int c = i / 24;
            int rem2 = i - c * 24;
            int rt = rem2 >> 2, qq = rem2 & 3;
            int ylo = ty0l + rt - 1;
            int cb = tx0l - 4 + qq * 4;
            float4 v = { 0.f, 0.f, 0.f, 0.f };
            if (ylo >= 0 && ylo < 128 && cb >= 0 && cb < 125)
                v = *(const float4*)(feat + (((size_t)(b * 128 + c)) << 14) + ylo * 128 + cb);
            const float* vp = (const float*)&v;
#pragma unroll
            for (int j = 0; j < 4; ++j) {
                int k = cb + j - (tx0l - 1);
                if (k >= 0 && k < 10)
                    lf2[(rt * 10 + k) * 140 + c] = vp[j];
            }
        }
    }
    __syncthreads();

    // ---- phase C: reassembly; thread = (x-pair, row, ch-quarter) -------
    {
        int cq = tid >> 6;                 // 0..3 -> 32 channels each
        int r  = (tid >> 3) & 7;
        int xp = tid & 7;
        int y = ty0 + r;
        int x0 = tx0 + 2 * xp;
        int pxA = r * 16 + 2 * xp;
        const float4 cA = *(const float4*)(coef + pxA * 4);
        const float4 cB = *(const float4*)(coef + pxA * 4 + 4);
        int py0 = (r >> 1) + (r & 1);
        int base0 = (py0 * 10 + xp) * 140;
        int base1 = base0 + 1400;
        float* op = out + (((size_t)b * 128) * 256 + y) * 256 + x0;
#pragma unroll 2
        for (int g8 = 0; g8 < 8; ++g8) {
            int cb = (cq * 8 + g8) * 4;
            float4 f00 = *(const float4*)(lf2 + base0 + cb);
            float4 f01 = *(const float4*)(lf2 + base0 + 140 + cb);
            float4 f02 = *(const float4*)(lf2 + base0 + 280 + cb);
            float4 f10 = *(const float4*)(lf2 + base1 + cb);
            float4 f11 = *(const float4*)(lf2 + base1 + 140 + cb);
            float4 f12 = *(const float4*)(lf2 + base1 + 280 + cb);
            const float* a00 = (const float*)&f00;
            const float* a01 = (const float*)&f01;
            const float* a02 = (const float*)&f02;
            const float* a10 = (const float*)&f10;
            const float* a11 = (const float*)&f11;
            const float* a12 = (const float*)&f12;
#pragma unroll
            for (int j = 0; j < 4; ++j) {
                float2 o;
                o.x = cA.x * a00[j] + cA.y * a01[j] + cA.z * a10[j] + cA.w * a11[j];
                o.y = cB.x * a01[j] + cB.y * a02[j] + cB.z * a11[j] + cB.w * a12[j];
                *(float2*)(op + (size_t)(cb + j) * 65536) = o;
            }
        }
    }
}

extern "C" void kernel_launch(void* const* d_in, const int* in_sizes, int n_in,
                              void* d_out, int out_size, void* d_ws, size_t ws_size,
                              hipStream_t stream)
{
    const float* feat  = (const float*)d_in[0];
    const float* guide = (const float*)d_in[1];
    const float* g_w1  = (const float*)d_in[2];
    const float* g_g1  = (const float*)d_in[3];
    const float* g_b1  = (const float*)d_in[4];
    const float* g_w2  = (const float*)d_in[5];
    const float* g_g2  = (const float*)d_in[6];
    const float* g_b2  = (const float*)d_in[7];
    const float* p_w   = (const float*)d_in[8];
    const float* k_w1  = (const float*)d_in[9];
    const float* k_w2  = (const float*)d_in[10];
    const float* k_b2  = (const float*)d_in[11];

    float* out = (float*)d_out;

    // bf16 NHWC intermediates inside d_out (dead before k_tail writes):
    ushort_t* x1 = (ushort_t*)out;                    // 4,194,304 bf16 = 8.4MB
    ushort_t* x2 = (ushort_t*)(out + 2097152);        // 4,194,304 bf16

    // workspace layout
    ushort_t* fs    = (ushort_t*)d_ws;                       // 2MB
    ushort_t* wpk   = (ushort_t*)((char*)d_ws + 2097152);    // 55,296B
    float*    partA = (float*)((char*)d_ws + 2152448);       // 512*64 f32 = 128KB
    float*    partB = (float*)((char*)d_ws + 2283520);       // 128KB
    ushort_t* w2pk  = wpk;
    ushort_t* kw1pk = wpk + 9216;

    k_phase1<<<876, 256, 0, stream>>>(guide, g_w1, g_w2, k_w1, p_w, feat,
                                      x1, fs, wpk, partA);
    k_conv2<<<512, 256, 0, stream>>>(x1, partA, g_g1, g_b1, w2pk, x2, partB);
    k_tail<<<1024, 256, 0, stream>>>(x2, partB, g_g2, g_b2, fs, kw1pk,
                                     k_w2, k_b2, feat, out);
}

// Round 14
// 71.282 us; speedup vs baseline: 1.0604x; 1.0604x over previous
//
#include <hip/hip_runtime.h>
#include <hip/hip_bf16.h>

#define EPS 1e-5f

// dims: feat (2,128,128,128) f32 NCHW, guide (2,3,256,256) f32 NCHW,
// out (2,128,256,256) f32 NCHW. E=32, K=3, k2=9. H2=W2=256.
// x1,x2 bf16 NHWC (2,256,256,32) in d_out; fs bf16 NHWC, packed weights,
// stats partials in d_ws. 3 launches; stats fused into producers (LDS tree),
// BN-ab reduced inline by consumers.  [round-12 best-known configuration]

typedef unsigned short ushort_t;
typedef __attribute__((ext_vector_type(8))) short short8v;   // 8 bf16 = 4 VGPR
typedef __attribute__((ext_vector_type(4))) float f32x4;

__device__ __forceinline__ int swz(int b) { return b ^ (((b >> 7) & 7) << 4); }
__device__ __forceinline__ float bf2f(ushort_t u) {
    unsigned int t = ((unsigned int)u) << 16;
    return __builtin_bit_cast(float, t);
}
__device__ __forceinline__ ushort_t f2bf(float f) {   // RNE via HW cvt
    __hip_bfloat16 h = (__hip_bfloat16)f;
    return __builtin_bit_cast(ushort_t, h);
}

// inline BN-coefficient reduction: part[512][64] -> red[320..384) = {a[32],b[32]}
__device__ __forceinline__ void ab_inline(
    const float* __restrict__ part, const float* __restrict__ gamma,
    const float* __restrict__ beta, float* red, int tid)
{
    int col = tid & 63, quart = tid >> 6;
    float s = 0.f;
    const float* p = part + (size_t)(quart * 128) * 64 + col;
#pragma unroll 8
    for (int bq = 0; bq < 128; ++bq) s += p[(size_t)bq * 64];
    red[quart * 64 + col] = s;
    __syncthreads();
    if (tid < 64)
        red[256 + tid] = red[tid] + red[64 + tid] + red[128 + tid] + red[192 + tid];
    __syncthreads();
    if (tid < 32) {
        float S  = red[256 + (tid >> 1) * 4 + (tid & 1) * 2];
        float SS = red[256 + (tid >> 1) * 4 + (tid & 1) * 2 + 1];
        const float n = 131072.f;
        float mean = S / n;
        float var = SS / n - mean * mean;
        float a = gamma[tid] * rsqrtf(var + EPS);
        red[320 + tid] = a;
        red[352 + tid] = beta[tid] - mean * a;
    }
    __syncthreads();
}

// ---- phase 1: conv1+stats | proj (local pw pack) | weight prep ----------
// grid: [0,512) conv1 | [512,768) proj | [768,876) prep
__global__ __launch_bounds__(256) void k_phase1(
    const float* __restrict__ guide, const float* __restrict__ w1,
    const float* __restrict__ w2, const float* __restrict__ kw1,
    const float* __restrict__ pw, const float* __restrict__ feat,
    ushort_t* __restrict__ x1, ushort_t* __restrict__ fs,
    ushort_t* __restrict__ wpk, float* __restrict__ part1)
{
    __shared__ __align__(16) char lds[40960];
    int tid = threadIdx.x;
    int blk = blockIdx.x;

    if (blk < 512) {
        // ---- conv1: guide 3->32, LDS-tiled, out bf16 NHWC + stats ----
        float* smu = (float*)lds;                    // [0, 4104)
        int b = blk >> 8;
        int tile = blk & 255;
        int ty0 = (tile >> 4) << 4, tx0 = (tile & 15) << 4;

        for (int i = tid; i < 972; i += 256) {
            int c = i / 324;
            int rem = i - c * 324;
            int r = rem / 18, cl = rem - r * 18;
            int yy = ty0 + r - 1, xx = tx0 + cl - 1;
            float v = 0.f;
            if (yy >= 0 && yy < 256 && xx >= 0 && xx < 256)
                v = guide[((b * 3 + c) * 256 + yy) * 256 + xx];
            smu[c * 342 + r * 19 + cl] = v;
        }
        __syncthreads();

        int r = tid >> 4, cl = tid & 15;
        float t[27];
#pragma unroll
        for (int c = 0; c < 3; ++c)
#pragma unroll
            for (int ky = 0; ky < 3; ++ky)
#pragma unroll
                for (int kx = 0; kx < 3; ++kx)
                    t[c * 9 + ky * 3 + kx] = smu[c * 342 + (r + ky) * 19 + cl + kx];
        int y = ty0 + r, x = tx0 + cl;
        float* sdump = (float*)(lds + 4224);         // [256 px][33] f32
        ushort_t pk[32];
#pragma unroll 4
        for (int e = 0; e < 32; ++e) {
            float acc = 0.f;
#pragma unroll
            for (int k = 0; k < 27; ++k)
                acc += t[k] * w1[e * 27 + k];
            pk[e] = f2bf(acc);
            sdump[tid * 33 + e] = bf2f(pk[e]);
        }
        ushort_t* dst = x1 + ((size_t)(b * 65536 + y * 256 + x)) * 32;
#pragma unroll
        for (int h = 0; h < 4; ++h)
            *(uint4*)(dst + h * 8) = *(uint4*)(pk + h * 8);

        // ---- per-block partial stats via LDS tree ----
        __syncthreads();
        {
            int ch = tid & 31, seg = tid >> 5;       // 8 segs x 32 px
            float s = 0.f, q = 0.f;
#pragma unroll 8
            for (int i = 0; i < 32; ++i) {
                float v = sdump[(seg * 32 + i) * 33 + ch];
                s += v; q += v * v;
            }
            float* segbuf = (float*)(lds + 38016);   // [256][2] f32
            segbuf[(seg * 32 + ch) * 2 + 0] = s;
            segbuf[(seg * 32 + ch) * 2 + 1] = q;
            __syncthreads();
            if (tid < 64) {
                int c = tid >> 1, isq = tid & 1;
                float tt = 0.f;
#pragma unroll
                for (int g = 0; g < 8; ++g)
                    tt += segbuf[(g * 32 + c) * 2 + isq];
                int col = (c >> 1) * 4 + (c & 1) * 2 + isq;
                part1[(size_t)blk * 64 + col] = tt;
            }
        }
    } else if (blk < 768) {
        // ---- proj: 1x1 conv 128->32 MFMA; pw packed into LDS locally ----
        int row = blk - 512;              // 0..255
        int b = row >> 7, yl = row & 127;
        ushort_t* pwl = (ushort_t*)(lds + 32768);     // 4096 bf16 B-frags

        for (int i = tid; i < 4096; i += 256) {
            int j = i & 7, l = (i >> 3) & 63, nt = (i >> 9) & 1, ks = i >> 10;
            int e = nt * 16 + (l & 15);
            int c = ks * 32 + (l >> 4) * 8 + j;
            pwl[i] = f2bf(pw[e * 128 + c]);
        }
        int x = tid & 127, cg = tid >> 7;
        const float* fb = feat + ((size_t)b << 21) + yl * 128 + x;
#pragma unroll
        for (int p = 0; p < 8; ++p) {
            int c0 = p * 16 + cg * 8;
            ushort_t pk[8];
#pragma unroll
            for (int j = 0; j < 8; ++j)
                pk[j] = f2bf(fb[(size_t)(c0 + j) << 14]);
            *(uint4*)(lds + swz(x * 256 + c0 * 2)) = *(uint4*)pk;
        }
        __syncthreads();

        int w = tid >> 6, l = tid & 63, lm = l & 15, lg = l >> 4;
        int px0 = w * 32;
        f32x4 acc[2][2] = {};
        const short8v* gB = (const short8v*)pwl;
#pragma unroll
        for (int ks = 0; ks < 4; ++ks) {
            short8v B0 = gB[(ks * 2 + 0) * 64 + l];
            short8v B1 = gB[(ks * 2 + 1) * 64 + l];
#pragma unroll
            for (int m = 0; m < 2; ++m) {
                short8v A = *(const short8v*)(
                    lds + swz((px0 + m * 16 + lm) * 256 + ks * 64 + lg * 16));
                acc[m][0] = __builtin_amdgcn_mfma_f32_16x16x32_bf16(A, B0, acc[m][0], 0, 0, 0);
                acc[m][1] = __builtin_amdgcn_mfma_f32_16x16x32_bf16(A, B1, acc[m][1], 0, 0, 0);
            }
        }
        __syncthreads();
#pragma unroll
        for (int m = 0; m < 2; ++m)
#pragma unroll
            for (int nt = 0; nt < 2; ++nt)
#pragma unroll
                for (int rg = 0; rg < 4; ++rg) {
                    int px = px0 + m * 16 + lg * 4 + rg;
                    int e = nt * 16 + lm;
                    *(ushort_t*)(lds + swz(px * 64 + e * 2)) =
                        f2bf(fmaxf(acc[m][nt][rg], 0.f));
                }
        __syncthreads();
        if (tid < 128) {
            ushort_t* dst = fs + ((size_t)(b * 16384 + yl * 128 + tid)) * 32;
#pragma unroll
            for (int h = 0; h < 4; ++h)
                *(uint4*)(dst + h * 8) = *(uint4*)(lds + swz(tid * 64 + h * 16));
        }
    } else {
        // ---- weight prep: w2 | kw1 into B-fragment order, bf16 ----
        int i = (blk - 768) * 256 + tid;     // 0..27647
        if (i < 9216) {
            int j = i & 7, l = (i >> 3) & 63, nt = (i >> 9) & 1, t = i >> 10;
            int e = nt * 16 + (l & 15);
            int k = (l >> 4) * 8 + j;
            wpk[i] = f2bf(w2[(e * 32 + k) * 9 + t]);
        } else {
            int i2 = i - 9216;
            int j = i2 & 7, l = (i2 >> 3) & 63, nt = (i2 >> 9) & 1;
            int kk = (i2 >> 10) & 1, t = i2 >> 11;
            int e = nt * 16 + (l & 15);
            int k = kk * 32 + (l >> 4) * 8 + j;
            wpk[i] = f2bf(kw1[(e * 64 + k) * 9 + t]);
        }
    }
}

// ---- conv2: bnrelu(x1) 32->32, bf16 MFMA; ab inline; stats fused -------
__global__ __launch_bounds__(256) void k_conv2(
    const ushort_t* __restrict__ x1, const float* __restrict__ part1,
    const float* __restrict__ gamma, const float* __restrict__ beta,
    const ushort_t* __restrict__ w2pk, ushort_t* __restrict__ x2,
    float* __restrict__ part2)
{
    __shared__ __align__(16) char lds[22784];    // 20736 staging + 2048 red/seg
    float* red = (float*)(lds + 20736);
    int tid = threadIdx.x;
    ab_inline(part1, gamma, beta, red, tid);
    const float* ab1 = red + 320;

    int b = blockIdx.x >> 8, tile = blockIdx.x & 255;
    int ty0 = (tile >> 4) << 4, tx0 = (tile & 15) << 4;

    for (int i = tid; i < 1296; i += 256) {
        int px = i >> 2, c8 = i & 3;
        int r = px / 18, cl = px - r * 18;
        int yy = ty0 + r - 1, xx = tx0 + cl - 1;
        ushort_t pk[8];
        if (yy >= 0 && yy < 256 && xx >= 0 && xx < 256) {
            const ushort_t* src = x1 + ((size_t)(b * 65536 + yy * 256 + xx)) * 32 + c8 * 8;
            uint4 raw = *(const uint4*)src;
            const ushort_t* rs = (const ushort_t*)&raw;
#pragma unroll
            for (int j = 0; j < 8; ++j) {
                int c = c8 * 8 + j;
                pk[j] = f2bf(fmaxf(ab1[c] * bf2f(rs[j]) + ab1[32 + c], 0.f));
            }
        } else {
#pragma unroll
            for (int j = 0; j < 8; ++j) pk[j] = 0;
        }
        *(uint4*)(lds + swz(px * 64 + c8 * 16)) = *(uint4*)pk;
    }
    __syncthreads();

    int w = tid >> 6, l = tid & 63, lm = l & 15, lg = l >> 4;
    f32x4 acc[4][2] = {};
    const short8v* gB = (const short8v*)w2pk;
#pragma unroll
    for (int t = 0; t < 9; ++t) {
        int ky = t / 3, kx = t % 3;
        short8v B0 = gB[(t * 2 + 0) * 64 + l];
        short8v B1 = gB[(t * 2 + 1) * 64 + l];
#pragma unroll
        for (int m = 0; m < 4; ++m) {
            int px = (w * 4 + m + ky) * 18 + lm + kx;
            short8v A = *(const short8v*)(lds + swz(px * 64 + lg * 16));
            acc[m][0] = __builtin_amdgcn_mfma_f32_16x16x32_bf16(A, B0, acc[m][0], 0, 0, 0);
            acc[m][1] = __builtin_amdgcn_mfma_f32_16x16x32_bf16(A, B1, acc[m][1], 0, 0, 0);
        }
    }
    __syncthreads();
#pragma unroll
    for (int m = 0; m < 4; ++m)
#pragma unroll
        for (int nt = 0; nt < 2; ++nt)
#pragma unroll
            for (int rg = 0; rg < 4; ++rg) {
                int px = (w * 4 + m) * 16 + lg * 4 + rg;
                int e = nt * 16 + lm;
                *(ushort_t*)(lds + swz(px * 64 + e * 2)) = f2bf(acc[m][nt][rg]);
            }
    __syncthreads();
    {
        int px = tid, r = px >> 4, cl = px & 15;
        int yy = ty0 + r, xx = tx0 + cl;
        ushort_t* dst = x2 + ((size_t)(b * 65536 + yy * 256 + xx)) * 32;
#pragma unroll
        for (int h = 0; h < 4; ++h)
            *(uint4*)(dst + h * 8) = *(uint4*)(lds + swz(px * 64 + h * 16));
    }

    // ---- fused stats of x2 tile straight from the bf16 LDS dump ----
    {
        int ch = tid & 31, seg = tid >> 5;
        float s = 0.f, q = 0.f;
#pragma unroll 8
        for (int i = 0; i < 32; ++i) {
            int px = seg * 32 + i;
            float v = bf2f(*(const ushort_t*)(lds + swz(px * 64 + ch * 2)));
            s += v; q += v * v;
        }
        float* segbuf = (float*)(lds + 20736);    // red region dead now
        __syncthreads();                          // ensure x2 reads done
        segbuf[(seg * 32 + ch) * 2 + 0] = s;
        segbuf[(seg * 32 + ch) * 2 + 1] = q;
        __syncthreads();
        if (tid < 64) {
            int c = tid >> 1, isq = tid & 1;
            float tt = 0.f;
#pragma unroll
            for (int g = 0; g < 8; ++g)
                tt += segbuf[(g * 32 + c) * 2 + isq];
            int col = (c >> 1) * 4 + (c & 1) * 2 + isq;
            part2[(size_t)blockIdx.x * 64 + col] = tt;
        }
    }
}

// ---- fused tail: conv3x3 64->32 (MFMA) + head + softmax + reassembly ---
// Tile = 16w x 8h highres; 1024 blocks; XCD-paired tile swizzle.
__global__ __launch_bounds__(256) void k_tail(
    const ushort_t* __restrict__ x2, const float* __restrict__ part2,
    const float* __restrict__ gamma, const float* __restrict__ beta,
    const ushort_t* __restrict__ fs, const ushort_t* __restrict__ kw1pk,
    const float* __restrict__ kw2, const float* __restrict__ kb2,
    const float* __restrict__ feat, float* __restrict__ out)
{
    // [0,32640): comb (23040B) -> head dump (16KB) -> lf2 (32640B)
    // [32640,38784): red scratch (1536B, dies) then zbuf 128 px * 12 f32
    __shared__ __align__(16) char lds[38784];
    int tid = threadIdx.x;

    // XCD-paired swizzle: adjacent-x tiles -> same XCD, adjacent dispatch.
    int p = blockIdx.x;                    // 1024
    int xcd = p & 7, q = p >> 3;
    int g = xcd * 64 + (q >> 1);           // tile-pair id, 512 total
    int b = g >> 8;
    int rem = g & 255;
    int ty0 = (rem >> 3) << 3;
    int tx0 = (((rem & 7) << 1) | (q & 1)) << 4;

    float* redz = (float*)(lds + 32640);
    ab_inline(part2, gamma, beta, redz, tid);
    const float* ab2 = redz + 320;         // dies when zbuf written (ok)

    // ---- phase A: stage comb tile [180 px (10x18 halo)][64 ch bf16] ----
    for (int i = tid; i < 1440; i += 256) {
        int px = i >> 3, c8 = i & 7;
        int r = px / 18, cl = px - r * 18;
        int yy = ty0 + r - 1, xx = tx0 + cl - 1;
        ushort_t pk[8];
        if (yy >= 0 && yy < 256 && xx >= 0 && xx < 256) {
            if (c8 < 4) {
                const ushort_t* src = x2 + ((size_t)(b * 65536 + yy * 256 + xx)) * 32 + c8 * 8;
                uint4 raw = *(const uint4*)src;
                const ushort_t* rs = (const ushort_t*)&raw;
#pragma unroll
                for (int j = 0; j < 8; ++j) {
                    int c = c8 * 8 + j;
                    pk[j] = f2bf(fmaxf(ab2[c] * bf2f(rs[j]) + ab2[32 + c], 0.f));
                }
            } else {
                const ushort_t* src = fs + ((size_t)(b * 16384 + (yy >> 1) * 128 + (xx >> 1))) * 32 + (c8 - 4) * 8;
                *(uint4*)pk = *(const uint4*)src;
            }
        } else {
#pragma unroll
            for (int j = 0; j < 8; ++j) pk[j] = 0;
        }
        *(uint4*)(lds + swz(px * 128 + c8 * 16)) = *(uint4*)pk;
    }
    __syncthreads();

    // ---- MFMA: 8 m-tiles (one output row each), 4 waves x 2 mt ---------
    int w = tid >> 6, l = tid & 63, lm = l & 15, lg = l >> 4;
    f32x4 acc[2][2] = {};
    {
        const short8v* gB = (const short8v*)kw1pk;
#pragma unroll
        for (int t = 0; t < 9; ++t) {
            int ky = t / 3, kx = t % 3;
#pragma unroll
            for (int kk = 0; kk < 2; ++kk) {
                short8v B0 = gB[(t * 4 + kk * 2 + 0) * 64 + l];
                short8v B1 = gB[(t * 4 + kk * 2 + 1) * 64 + l];
#pragma unroll
                for (int m = 0; m < 2; ++m) {
                    int mt = w * 2 + m;
                    int px = (mt + ky) * 18 + lm + kx;
                    short8v A = *(const short8v*)(lds + swz(px * 128 + kk * 64 + lg * 16));
                    acc[m][0] = __builtin_amdgcn_mfma_f32_16x16x32_bf16(A, B0, acc[m][0], 0, 0, 0);
                    acc[m][1] = __builtin_amdgcn_mfma_f32_16x16x32_bf16(A, B1, acc[m][1], 0, 0, 0);
                }
            }
        }
    }
    __syncthreads();
#pragma unroll
    for (int m = 0; m < 2; ++m)
#pragma unroll
        for (int nt = 0; nt < 2; ++nt)
#pragma unroll
            for (int rg = 0; rg < 4; ++rg) {
                int px = (w * 2 + m) * 16 + lg * 4 + rg;
                int e = nt * 16 + lm;
                *(float*)(lds + swz(px * 128 + e * 4)) = acc[m][nt][rg];
            }
    __syncthreads();

    // ---- head (tid<128): ReLU -> 1x1 -> softmax -> zbuf ----------------
    float* zbuf = (float*)(lds + 32640);
    if (tid < 128) {
        int px = tid;
        float v[32];
#pragma unroll
        for (int h = 0; h < 8; ++h) {
            float4 qd = *(const float4*)(lds + swz(px * 128 + h * 16));
            v[h * 4 + 0] = qd.x; v[h * 4 + 1] = qd.y; v[h * 4 + 2] = qd.z; v[h * 4 + 3] = qd.w;
        }
        float z[9];
#pragma unroll
        for (int i = 0; i < 9; ++i) z[i] = kb2[i];
#pragma unroll
        for (int e = 0; e < 32; ++e) {
            float ae = fmaxf(v[e], 0.f);
#pragma unroll
            for (int i = 0; i < 9; ++i)
                z[i] += ae * kw2[i * 32 + e];
        }
        float m = z[0];
#pragma unroll
        for (int i = 1; i < 9; ++i) m = fmaxf(m, z[i]);
        float sum = 0.f;
#pragma unroll
        for (int i = 0; i < 9; ++i) { z[i] = expf(z[i] - m); sum += z[i]; }
        float inv = 1.f / sum;
#pragma unroll
        for (int i = 0; i < 9; ++i) zbuf[px * 12 + i] = z[i] * inv;
    }
    __syncthreads();

    // ---- phase B: stage feat fp32 pos-major [60 pos][136 ch-pad] -------
    float* lf2 = (float*)lds;
    {
        int ty0l = ty0 >> 1, tx0l = tx0 >> 1;
        for (int i = tid; i < 3072; i += 256) {     // 128 ch * 6 rows * 4 q
            int c = i / 24;
            int rem2 = i - c * 24;
            int rt = rem2 >> 2, qq = rem2 & 3;
            int ylo = ty0l + rt - 1;
            int cb = tx0l - 4 + qq * 4;
            float4 v = { 0.f, 0.f, 0.f, 0.f };
            if (ylo >= 0 && ylo < 128 && cb >= 0 && cb < 125)
                v = *(const float4*)(feat + (((size_t)(b * 128 + c)) << 14) + ylo * 128 + cb);
            const float* vp = (const float*)&v;
#pragma unroll
            for (int j = 0; j < 4; ++j) {
                int k = cb + j - (tx0l - 1);
                if (k >= 0 && k < 10)
                    lf2[(rt * 10 + k) * 136 + c] = vp[j];
            }
        }
    }
    __syncthreads();

    // ---- phase C: reassembly; thread = (px, chalf); vectorized reads ---
    {
        int px = tid & 127, chalf = tid >> 7;
        int r = px >> 4, cl = px & 15;
        int y = ty0 + r, x = tx0 + cl;
        int ry = r & 1, rx = cl & 1;
        float z[9];
#pragma unroll
        for (int i = 0; i < 9; ++i) z[i] = zbuf[px * 12 + i];
        float zr[2][3];
#pragma unroll
        for (int dx = 0; dx < 3; ++dx) {
            if (ry == 0) { zr[0][dx] = z[dx];             zr[1][dx] = z[3 + dx] + z[6 + dx]; }
            else         { zr[0][dx] = z[dx] + z[3 + dx]; zr[1][dx] = z[6 + dx]; }
        }
        float co00, co01, co10, co11;
        if (rx == 0) { co00 = zr[0][0];            co01 = zr[0][1] + zr[0][2];
                       co10 = zr[1][0];            co11 = zr[1][1] + zr[1][2]; }
        else         { co00 = zr[0][0] + zr[0][1]; co01 = zr[0][2];
                       co10 = zr[1][0] + zr[1][1]; co11 = zr[1][2]; }
        int py0 = (r >> 1) + ry, px0c = (cl >> 1) + rx;
        int p00 = py0 * 10 + px0c;
        float* op = out + (((size_t)b * 128) * 256 + y) * 256 + x;
#pragma unroll 4
        for (int gg = 0; gg < 16; ++gg) {
            int c4 = chalf * 16 + gg;
            float4 f00 = *(const float4*)(lf2 + p00 * 136 + c4 * 4);
            float4 f01 = *(const float4*)(lf2 + (p00 + 1) * 136 + c4 * 4);
            float4 f10 = *(const float4*)(lf2 + (p00 + 10) * 136 + c4 * 4);
            float4 f11 = *(const float4*)(lf2 + (p00 + 11) * 136 + c4 * 4);
            const float* a00 = (const float*)&f00;
            const float* a01 = (const float*)&f01;
            const float* a10 = (const float*)&f10;
            const float* a11 = (const float*)&f11;
#pragma unroll
            for (int j = 0; j < 4; ++j) {
                float o = co00 * a00[j] + co01 * a01[j]
                        + co10 * a10[j] + co11 * a11[j];
                op[(size_t)(c4 * 4 + j) * 65536] = o;
            }
        }
    }
}

extern "C" void kernel_launch(void* const* d_in, const int* in_sizes, int n_in,
                              void* d_out, int out_size, void* d_ws, size_t ws_size,
                              hipStream_t stream)
{
    const float* feat  = (const float*)d_in[0];
    const float* guide = (const float*)d_in[1];
    const float* g_w1  = (const float*)d_in[2];
    const float* g_g1  = (const float*)d_in[3];
    const float* g_b1  = (const float*)d_in[4];
    const float* g_w2  = (const float*)d_in[5];
    const float* g_g2  = (const float*)d_in[6];
    const float* g_b2  = (const float*)d_in[7];
    const float* p_w   = (const float*)d_in[8];
    const float* k_w1  = (const float*)d_in[9];
    const float* k_w2  = (const float*)d_in[10];
    const float* k_b2  = (const float*)d_in[11];

    float* out = (float*)d_out;

    // bf16 NHWC intermediates inside d_out (dead before k_tail writes):
    ushort_t* x1 = (ushort_t*)out;                    // 4,194,304 bf16 = 8.4MB
    ushort_t* x2 = (ushort_t*)(out + 2097152);        // 4,194,304 bf16

    // workspace layout
    ushort_t* fs    = (ushort_t*)d_ws;                       // 2MB
    ushort_t* wpk   = (ushort_t*)((char*)d_ws + 2097152);    // 55,296B
    float*    partA = (float*)((char*)d_ws + 2152448);       // 512*64 f32 = 128KB
    float*    partB = (float*)((char*)d_ws + 2283520);       // 128KB
    ushort_t* w2pk  = wpk;
    ushort_t* kw1pk = wpk + 9216;

    k_phase1<<<876, 256, 0, stream>>>(guide, g_w1, g_w2, k_w1, p_w, feat,
                                      x1, fs, wpk, partA);
    k_conv2<<<512, 256, 0, stream>>>(x1, partA, g_g1, g_b1, w2pk, x2, partB);
    k_tail<<<1024, 256, 0, stream>>>(x2, partB, g_g2, g_b2, fs, kw1pk,
                                     k_w2, k_b2, feat, out);
}

// Round 15
// 71.244 us; speedup vs baseline: 1.0610x; 1.0005x over previous
//
#include <hip/hip_runtime.h>
#include <hip/hip_bf16.h>

#define EPS 1e-5f

// dims: feat (2,128,128,128) f32 NCHW, guide (2,3,256,256) f32 NCHW,
// out (2,128,256,256) f32 NCHW. E=32, K=3, k2=9. H2=W2=256.
// x1,x2 bf16 NHWC (2,256,256,32) in d_out; fs bf16 NHWC, packed weights,
// stats partials in d_ws. 3 launches; stats fused into producers (LDS tree),
// BN-ab reduced inline by consumers.
// [round-14 base + head-side parity-collapse (coef float4) — single change]

typedef unsigned short ushort_t;
typedef __attribute__((ext_vector_type(8))) short short8v;   // 8 bf16 = 4 VGPR
typedef __attribute__((ext_vector_type(4))) float f32x4;

__device__ __forceinline__ int swz(int b) { return b ^ (((b >> 7) & 7) << 4); }
__device__ __forceinline__ float bf2f(ushort_t u) {
    unsigned int t = ((unsigned int)u) << 16;
    return __builtin_bit_cast(float, t);
}
__device__ __forceinline__ ushort_t f2bf(float f) {   // RNE via HW cvt
    __hip_bfloat16 h = (__hip_bfloat16)f;
    return __builtin_bit_cast(ushort_t, h);
}

// inline BN-coefficient reduction: part[512][64] -> red[320..384) = {a[32],b[32]}
__device__ __forceinline__ void ab_inline(
    const float* __restrict__ part, const float* __restrict__ gamma,
    const float* __restrict__ beta, float* red, int tid)
{
    int col = tid & 63, quart = tid >> 6;
    float s = 0.f;
    const float* p = part + (size_t)(quart * 128) * 64 + col;
#pragma unroll 8
    for (int bq = 0; bq < 128; ++bq) s += p[(size_t)bq * 64];
    red[quart * 64 + col] = s;
    __syncthreads();
    if (tid < 64)
        red[256 + tid] = red[tid] + red[64 + tid] + red[128 + tid] + red[192 + tid];
    __syncthreads();
    if (tid < 32) {
        float S  = red[256 + (tid >> 1) * 4 + (tid & 1) * 2];
        float SS = red[256 + (tid >> 1) * 4 + (tid & 1) * 2 + 1];
        const float n = 131072.f;
        float mean = S / n;
        float var = SS / n - mean * mean;
        float a = gamma[tid] * rsqrtf(var + EPS);
        red[320 + tid] = a;
        red[352 + tid] = beta[tid] - mean * a;
    }
    __syncthreads();
}

// ---- phase 1: conv1+stats | proj (local pw pack) | weight prep ----------
// grid: [0,512) conv1 | [512,768) proj | [768,876) prep
__global__ __launch_bounds__(256) void k_phase1(
    const float* __restrict__ guide, const float* __restrict__ w1,
    const float* __restrict__ w2, const float* __restrict__ kw1,
    const float* __restrict__ pw, const float* __restrict__ feat,
    ushort_t* __restrict__ x1, ushort_t* __restrict__ fs,
    ushort_t* __restrict__ wpk, float* __restrict__ part1)
{
    __shared__ __align__(16) char lds[40960];
    int tid = threadIdx.x;
    int blk = blockIdx.x;

    if (blk < 512) {
        // ---- conv1: guide 3->32, LDS-tiled, out bf16 NHWC + stats ----
        float* smu = (float*)lds;                    // [0, 4104)
        int b = blk >> 8;
        int tile = blk & 255;
        int ty0 = (tile >> 4) << 4, tx0 = (tile & 15) << 4;

        for (int i = tid; i < 972; i += 256) {
            int c = i / 324;
            int rem = i - c * 324;
            int r = rem / 18, cl = rem - r * 18;
            int yy = ty0 + r - 1, xx = tx0 + cl - 1;
            float v = 0.f;
            if (yy >= 0 && yy < 256 && xx >= 0 && xx < 256)
                v = guide[((b * 3 + c) * 256 + yy) * 256 + xx];
            smu[c * 342 + r * 19 + cl] = v;
        }
        __syncthreads();

        int r = tid >> 4, cl = tid & 15;
        float t[27];
#pragma unroll
        for (int c = 0; c < 3; ++c)
#pragma unroll
            for (int ky = 0; ky < 3; ++ky)
#pragma unroll
                for (int kx = 0; kx < 3; ++kx)
                    t[c * 9 + ky * 3 + kx] = smu[c * 342 + (r + ky) * 19 + cl + kx];
        int y = ty0 + r, x = tx0 + cl;
        float* sdump = (float*)(lds + 4224);         // [256 px][33] f32
        ushort_t pk[32];
#pragma unroll 4
        for (int e = 0; e < 32; ++e) {
            float acc = 0.f;
#pragma unroll
            for (int k = 0; k < 27; ++k)
                acc += t[k] * w1[e * 27 + k];
            pk[e] = f2bf(acc);
            sdump[tid * 33 + e] = bf2f(pk[e]);
        }
        ushort_t* dst = x1 + ((size_t)(b * 65536 + y * 256 + x)) * 32;
#pragma unroll
        for (int h = 0; h < 4; ++h)
            *(uint4*)(dst + h * 8) = *(uint4*)(pk + h * 8);

        // ---- per-block partial stats via LDS tree ----
        __syncthreads();
        {
            int ch = tid & 31, seg = tid >> 5;       // 8 segs x 32 px
            float s = 0.f, q = 0.f;
#pragma unroll 8
            for (int i = 0; i < 32; ++i) {
                float v = sdump[(seg * 32 + i) * 33 + ch];
                s += v; q += v * v;
            }
            float* segbuf = (float*)(lds + 38016);   // [256][2] f32
            segbuf[(seg * 32 + ch) * 2 + 0] = s;
            segbuf[(seg * 32 + ch) * 2 + 1] = q;
            __syncthreads();
            if (tid < 64) {
                int c = tid >> 1, isq = tid & 1;
                float tt = 0.f;
#pragma unroll
                for (int g = 0; g < 8; ++g)
                    tt += segbuf[(g * 32 + c) * 2 + isq];
                int col = (c >> 1) * 4 + (c & 1) * 2 + isq;
                part1[(size_t)blk * 64 + col] = tt;
            }
        }
    } else if (blk < 768) {
        // ---- proj: 1x1 conv 128->32 MFMA; pw packed into LDS locally ----
        int row = blk - 512;              // 0..255
        int b = row >> 7, yl = row & 127;
        ushort_t* pwl = (ushort_t*)(lds + 32768);     // 4096 bf16 B-frags

        for (int i = tid; i < 4096; i += 256) {
            int j = i & 7, l = (i >> 3) & 63, nt = (i >> 9) & 1, ks = i >> 10;
            int e = nt * 16 + (l & 15);
            int c = ks * 32 + (l >> 4) * 8 + j;
            pwl[i] = f2bf(pw[e * 128 + c]);
        }
        int x = tid & 127, cg = tid >> 7;
        const float* fb = feat + ((size_t)b << 21) + yl * 128 + x;
#pragma unroll
        for (int p = 0; p < 8; ++p) {
            int c0 = p * 16 + cg * 8;
            ushort_t pk[8];
#pragma unroll
            for (int j = 0; j < 8; ++j)
                pk[j] = f2bf(fb[(size_t)(c0 + j) << 14]);
            *(uint4*)(lds + swz(x * 256 + c0 * 2)) = *(uint4*)pk;
        }
        __syncthreads();

        int w = tid >> 6, l = tid & 63, lm = l & 15, lg = l >> 4;
        int px0 = w * 32;
        f32x4 acc[2][2] = {};
        const short8v* gB = (const short8v*)pwl;
#pragma unroll
        for (int ks = 0; ks < 4; ++ks) {
            short8v B0 = gB[(ks * 2 + 0) * 64 + l];
            short8v B1 = gB[(ks * 2 + 1) * 64 + l];
#pragma unroll
            for (int m = 0; m < 2; ++m) {
                short8v A = *(const short8v*)(
                    lds + swz((px0 + m * 16 + lm) * 256 + ks * 64 + lg * 16));
                acc[m][0] = __builtin_amdgcn_mfma_f32_16x16x32_bf16(A, B0, acc[m][0], 0, 0, 0);
                acc[m][1] = __builtin_amdgcn_mfma_f32_16x16x32_bf16(A, B1, acc[m][1], 0, 0, 0);
            }
        }
        __syncthreads();
#pragma unroll
        for (int m = 0; m < 2; ++m)
#pragma unroll
            for (int nt = 0; nt < 2; ++nt)
#pragma unroll
                for (int rg = 0; rg < 4; ++rg) {
                    int px = px0 + m * 16 + lg * 4 + rg;
                    int e = nt * 16 + lm;
                    *(ushort_t*)(lds + swz(px * 64 + e * 2)) =
                        f2bf(fmaxf(acc[m][nt][rg], 0.f));
                }
        __syncthreads();
        if (tid < 128) {
            ushort_t* dst = fs + ((size_t)(b * 16384 + yl * 128 + tid)) * 32;
#pragma unroll
            for (int h = 0; h < 4; ++h)
                *(uint4*)(dst + h * 8) = *(uint4*)(lds + swz(tid * 64 + h * 16));
        }
    } else {
        // ---- weight prep: w2 | kw1 into B-fragment order, bf16 ----
        int i = (blk - 768) * 256 + tid;     // 0..27647
        if (i < 9216) {
            int j = i & 7, l = (i >> 3) & 63, nt = (i >> 9) & 1, t = i >> 10;
            int e = nt * 16 + (l & 15);
            int k = (l >> 4) * 8 + j;
            wpk[i] = f2bf(w2[(e * 32 + k) * 9 + t]);
        } else {
            int i2 = i - 9216;
            int j = i2 & 7, l = (i2 >> 3) & 63, nt = (i2 >> 9) & 1;
            int kk = (i2 >> 10) & 1, t = i2 >> 11;
            int e = nt * 16 + (l & 15);
            int k = kk * 32 + (l >> 4) * 8 + j;
            wpk[i] = f2bf(kw1[(e * 64 + k) * 9 + t]);
        }
    }
}

// ---- conv2: bnrelu(x1) 32->32, bf16 MFMA; ab inline; stats fused -------
__global__ __launch_bounds__(256) void k_conv2(
    const ushort_t* __restrict__ x1, const float* __restrict__ part1,
    const float* __restrict__ gamma, const float* __restrict__ beta,
    const ushort_t* __restrict__ w2pk, ushort_t* __restrict__ x2,
    float* __restrict__ part2)
{
    __shared__ __align__(16) char lds[22784];    // 20736 staging + 2048 red/seg
    float* red = (float*)(lds + 20736);
    int tid = threadIdx.x;
    ab_inline(part1, gamma, beta, red, tid);
    const float* ab1 = red + 320;

    int b = blockIdx.x >> 8, tile = blockIdx.x & 255;
    int ty0 = (tile >> 4) << 4, tx0 = (tile & 15) << 4;

    for (int i = tid; i < 1296; i += 256) {
        int px = i >> 2, c8 = i & 3;
        int r = px / 18, cl = px - r * 18;
        int yy = ty0 + r - 1, xx = tx0 + cl - 1;
        ushort_t pk[8];
        if (yy >= 0 && yy < 256 && xx >= 0 && xx < 256) {
            const ushort_t* src = x1 + ((size_t)(b * 65536 + yy * 256 + xx)) * 32 + c8 * 8;
            uint4 raw = *(const uint4*)src;
            const ushort_t* rs = (const ushort_t*)&raw;
#pragma unroll
            for (int j = 0; j < 8; ++j) {
                int c = c8 * 8 + j;
                pk[j] = f2bf(fmaxf(ab1[c] * bf2f(rs[j]) + ab1[32 + c], 0.f));
            }
        } else {
#pragma unroll
            for (int j = 0; j < 8; ++j) pk[j] = 0;
        }
        *(uint4*)(lds + swz(px * 64 + c8 * 16)) = *(uint4*)pk;
    }
    __syncthreads();

    int w = tid >> 6, l = tid & 63, lm = l & 15, lg = l >> 4;
    f32x4 acc[4][2] = {};
    const short8v* gB = (const short8v*)w2pk;
#pragma unroll
    for (int t = 0; t < 9; ++t) {
        int ky = t / 3, kx = t % 3;
        short8v B0 = gB[(t * 2 + 0) * 64 + l];
        short8v B1 = gB[(t * 2 + 1) * 64 + l];
#pragma unroll
        for (int m = 0; m < 4; ++m) {
            int px = (w * 4 + m + ky) * 18 + lm + kx;
            short8v A = *(const short8v*)(lds + swz(px * 64 + lg * 16));
            acc[m][0] = __builtin_amdgcn_mfma_f32_16x16x32_bf16(A, B0, acc[m][0], 0, 0, 0);
            acc[m][1] = __builtin_amdgcn_mfma_f32_16x16x32_bf16(A, B1, acc[m][1], 0, 0, 0);
        }
    }
    __syncthreads();
#pragma unroll
    for (int m = 0; m < 4; ++m)
#pragma unroll
        for (int nt = 0; nt < 2; ++nt)
#pragma unroll
            for (int rg = 0; rg < 4; ++rg) {
                int px = (w * 4 + m) * 16 + lg * 4 + rg;
                int e = nt * 16 + lm;
                *(ushort_t*)(lds + swz(px * 64 + e * 2)) = f2bf(acc[m][nt][rg]);
            }
    __syncthreads();
    {
        int px = tid, r = px >> 4, cl = px & 15;
        int yy = ty0 + r, xx = tx0 + cl;
        ushort_t* dst = x2 + ((size_t)(b * 65536 + yy * 256 + xx)) * 32;
#pragma unroll
        for (int h = 0; h < 4; ++h)
            *(uint4*)(dst + h * 8) = *(uint4*)(lds + swz(px * 64 + h * 16));
    }

    // ---- fused stats of x2 tile straight from the bf16 LDS dump ----
    {
        int ch = tid & 31, seg = tid >> 5;
        float s = 0.f, q = 0.f;
#pragma unroll 8
        for (int i = 0; i < 32; ++i) {
            int px = seg * 32 + i;
            float v = bf2f(*(const ushort_t*)(lds + swz(px * 64 + ch * 2)));
            s += v; q += v * v;
        }
        float* segbuf = (float*)(lds + 20736);    // red region dead now
        __syncthreads();                          // ensure x2 reads done
        segbuf[(seg * 32 + ch) * 2 + 0] = s;
        segbuf[(seg * 32 + ch) * 2 + 1] = q;
        __syncthreads();
        if (tid < 64) {
            int c = tid >> 1, isq = tid & 1;
            float tt = 0.f;
#pragma unroll
            for (int g = 0; g < 8; ++g)
                tt += segbuf[(g * 32 + c) * 2 + isq];
            int col = (c >> 1) * 4 + (c & 1) * 2 + isq;
            part2[(size_t)blockIdx.x * 64 + col] = tt;
        }
    }
}

// ---- fused tail: conv3x3 64->32 (MFMA) + head + softmax + reassembly ---
// Tile = 16w x 8h highres; 1024 blocks; XCD-paired tile swizzle.
__global__ __launch_bounds__(256) void k_tail(
    const ushort_t* __restrict__ x2, const float* __restrict__ part2,
    const float* __restrict__ gamma, const float* __restrict__ beta,
    const ushort_t* __restrict__ fs, const ushort_t* __restrict__ kw1pk,
    const float* __restrict__ kw2, const float* __restrict__ kb2,
    const float* __restrict__ feat, float* __restrict__ out)
{
    // [0,32640): comb (23040B) -> head dump (16KB) -> lf2 (32640B)
    // [32640,38784): red scratch (1536B, dies) then coef 128 px * 4 f32
    __shared__ __align__(16) char lds[38784];
    int tid = threadIdx.x;

    // XCD-paired swizzle: adjacent-x tiles -> same XCD, adjacent dispatch.
    int p = blockIdx.x;                    // 1024
    int xcd = p & 7, q = p >> 3;
    int g = xcd * 64 + (q >> 1);           // tile-pair id, 512 total
    int b = g >> 8;
    int rem = g & 255;
    int ty0 = (rem >> 3) << 3;
    int tx0 = (((rem & 7) << 1) | (q & 1)) << 4;

    float* redz = (float*)(lds + 32640);
    ab_inline(part2, gamma, beta, redz, tid);
    const float* ab2 = redz + 320;         // dies when coef written (ok)

    // ---- phase A: stage comb tile [180 px (10x18 halo)][64 ch bf16] ----
    for (int i = tid; i < 1440; i += 256) {
        int px = i >> 3, c8 = i & 7;
        int r = px / 18, cl = px - r * 18;
        int yy = ty0 + r - 1, xx = tx0 + cl - 1;
        ushort_t pk[8];
        if (yy >= 0 && yy < 256 && xx >= 0 && xx < 256) {
            if (c8 < 4) {
                const ushort_t* src = x2 + ((size_t)(b * 65536 + yy * 256 + xx)) * 32 + c8 * 8;
                uint4 raw = *(const uint4*)src;
                const ushort_t* rs = (const ushort_t*)&raw;
#pragma unroll
                for (int j = 0; j < 8; ++j) {
                    int c = c8 * 8 + j;
                    pk[j] = f2bf(fmaxf(ab2[c] * bf2f(rs[j]) + ab2[32 + c], 0.f));
                }
            } else {
                const ushort_t* src = fs + ((size_t)(b * 16384 + (yy >> 1) * 128 + (xx >> 1))) * 32 + (c8 - 4) * 8;
                *(uint4*)pk = *(const uint4*)src;
            }
        } else {
#pragma unroll
            for (int j = 0; j < 8; ++j) pk[j] = 0;
        }
        *(uint4*)(lds + swz(px * 128 + c8 * 16)) = *(uint4*)pk;
    }
    __syncthreads();

    // ---- MFMA: 8 m-tiles (one output row each), 4 waves x 2 mt ---------
    int w = tid >> 6, l = tid & 63, lm = l & 15, lg = l >> 4;
    f32x4 acc[2][2] = {};
    {
        const short8v* gB = (const short8v*)kw1pk;
#pragma unroll
        for (int t = 0; t < 9; ++t) {
            int ky = t / 3, kx = t % 3;
#pragma unroll
            for (int kk = 0; kk < 2; ++kk) {
                short8v B0 = gB[(t * 4 + kk * 2 + 0) * 64 + l];
                short8v B1 = gB[(t * 4 + kk * 2 + 1) * 64 + l];
#pragma unroll
                for (int m = 0; m < 2; ++m) {
                    int mt = w * 2 + m;
                    int px = (mt + ky) * 18 + lm + kx;
                    short8v A = *(const short8v*)(lds + swz(px * 128 + kk * 64 + lg * 16));
                    acc[m][0] = __builtin_amdgcn_mfma_f32_16x16x32_bf16(A, B0, acc[m][0], 0, 0, 0);
                    acc[m][1] = __builtin_amdgcn_mfma_f32_16x16x32_bf16(A, B1, acc[m][1], 0, 0, 0);
                }
            }
        }
    }
    __syncthreads();
#pragma unroll
    for (int m = 0; m < 2; ++m)
#pragma unroll
        for (int nt = 0; nt < 2; ++nt)
#pragma unroll
            for (int rg = 0; rg < 4; ++rg) {
                int px = (w * 2 + m) * 16 + lg * 4 + rg;
                int e = nt * 16 + lm;
                *(float*)(lds + swz(px * 128 + e * 4)) = acc[m][nt][rg];
            }
    __syncthreads();

    // ---- head (tid<128): ReLU -> 1x1 -> softmax -> collapsed coef ------
    float* coef = (float*)(lds + 32640);       // red region dead
    if (tid < 128) {
        int px = tid;
        float v[32];
#pragma unroll
        for (int h = 0; h < 8; ++h) {
            float4 qd = *(const float4*)(lds + swz(px * 128 + h * 16));
            v[h * 4 + 0] = qd.x; v[h * 4 + 1] = qd.y; v[h * 4 + 2] = qd.z; v[h * 4 + 3] = qd.w;
        }
        float z[9];
#pragma unroll
        for (int i = 0; i < 9; ++i) z[i] = kb2[i];
#pragma unroll
        for (int e = 0; e < 32; ++e) {
            float ae = fmaxf(v[e], 0.f);
#pragma unroll
            for (int i = 0; i < 9; ++i)
                z[i] += ae * kw2[i * 32 + e];
        }
        float m = z[0];
#pragma unroll
        for (int i = 1; i < 9; ++i) m = fmaxf(m, z[i]);
        float sum = 0.f;
#pragma unroll
        for (int i = 0; i < 9; ++i) { z[i] = expf(z[i] - m); sum += z[i]; }
        float inv = 1.f / sum;
#pragma unroll
        for (int i = 0; i < 9; ++i) z[i] *= inv;
        // parity-collapse (same arithmetic/order as old phase C)
        int r = px >> 4, cl = px & 15;
        int ry = r & 1, rx = cl & 1;
        float zr[2][3];
#pragma unroll
        for (int dx = 0; dx < 3; ++dx) {
            if (ry == 0) { zr[0][dx] = z[dx];             zr[1][dx] = z[3 + dx] + z[6 + dx]; }
            else         { zr[0][dx] = z[dx] + z[3 + dx]; zr[1][dx] = z[6 + dx]; }
        }
        float4 cf;
        if (rx == 0) { cf.x = zr[0][0];            cf.y = zr[0][1] + zr[0][2];
                       cf.z = zr[1][0];            cf.w = zr[1][1] + zr[1][2]; }
        else         { cf.x = zr[0][0] + zr[0][1]; cf.y = zr[0][2];
                       cf.z = zr[1][0] + zr[1][1]; cf.w = zr[1][2]; }
        *(float4*)(coef + px * 4) = cf;
    }
    __syncthreads();

    // ---- phase B: stage feat fp32 pos-major [60 pos][136 ch-pad] -------
    float* lf2 = (float*)lds;
    {
        int ty0l = ty0 >> 1, tx0l = tx0 >> 1;
        for (int i = tid; i < 3072; i += 256) {     // 128 ch * 6 rows * 4 q
            int c = i / 24;
            int rem2 = i - c * 24;
            int rt = rem2 >> 2, qq = rem2 & 3;
            int ylo = ty0l + rt - 1;
            int cb = tx0l - 4 + qq * 4;
            float4 v = { 0.f, 0.f, 0.f, 0.f };
            if (ylo >= 0 && ylo < 128 && cb >= 0 && cb < 125)
                v = *(const float4*)(feat + (((size_t)(b * 128 + c)) << 14) + ylo * 128 + cb);
            const float* vp = (const float*)&v;
#pragma unroll
            for (int j = 0; j < 4; ++j) {
                int k = cb + j - (tx0l - 1);
                if (k >= 0 && k < 10)
                    lf2[(rt * 10 + k) * 136 + c] = vp[j];
            }
        }
    }
    __syncthreads();

    // ---- phase C: reassembly; thread = (px, chalf); vectorized reads ---
    {
        int px = tid & 127, chalf = tid >> 7;
        int r = px >> 4, cl = px & 15;
        int y = ty0 + r, x = tx0 + cl;
        int ry = r & 1, rx = cl & 1;
        const float4 cf = *(const float4*)(coef + px * 4);
        float co00 = cf.x, co01 = cf.y, co10 = cf.z, co11 = cf.w;
        int py0 = (r >> 1) + ry, px0c = (cl >> 1) + rx;
        int p00 = py0 * 10 + px0c;
        float* op = out + (((size_t)b * 128) * 256 + y) * 256 + x;
#pragma unroll 4
        for (int gg = 0; gg < 16; ++gg) {
            int c4 = chalf * 16 + gg;
            float4 f00 = *(const float4*)(lf2 + p00 * 136 + c4 * 4);
            float4 f01 = *(const float4*)(lf2 + (p00 + 1) * 136 + c4 * 4);
            float4 f10 = *(const float4*)(lf2 + (p00 + 10) * 136 + c4 * 4);
            float4 f11 = *(const float4*)(lf2 + (p00 + 11) * 136 + c4 * 4);
            const float* a00 = (const float*)&f00;
            const float* a01 = (const float*)&f01;
            const float* a10 = (const float*)&f10;
            const float* a11 = (const float*)&f11;
#pragma unroll
            for (int j = 0; j < 4; ++j) {
                float o = co00 * a00[j] + co01 * a01[j]
                        + co10 * a10[j] + co11 * a11[j];
                op[(size_t)(c4 * 4 + j) * 65536] = o;
            }
        }
    }
}

extern "C" void kernel_launch(void* const* d_in, const int* in_sizes, int n_in,
                              void* d_out, int out_size, void* d_ws, size_t ws_size,
                              hipStream_t stream)
{
    const float* feat  = (const float*)d_in[0];
    const float* guide = (const float*)d_in[1];
    const float* g_w1  = (const float*)d_in[2];
    const float* g_g1  = (const float*)d_in[3];
    const float* g_b1  = (const float*)d_in[4];
    const float* g_w2  = (const float*)d_in[5];
    const float* g_g2  = (const float*)d_in[6];
    const float* g_b2  = (const float*)d_in[7];
    const float* p_w   = (const float*)d_in[8];
    const float* k_w1  = (const float*)d_in[9];
    const float* k_w2  = (const float*)d_in[10];
    const float* k_b2  = (const float*)d_in[11];

    float* out = (float*)d_out;

    // bf16 NHWC intermediates inside d_out (dead before k_tail writes):
    ushort_t* x1 = (ushort_t*)out;                    // 4,194,304 bf16 = 8.4MB
    ushort_t* x2 = (ushort_t*)(out + 2097152);        // 4,194,304 bf16

    // workspace layout
    ushort_t* fs    = (ushort_t*)d_ws;                       // 2MB
    ushort_t* wpk   = (ushort_t*)((char*)d_ws + 2097152);    // 55,296B
    float*    partA = (float*)((char*)d_ws + 2152448);       // 512*64 f32 = 128KB
    float*    partB = (float*)((char*)d_ws + 2283520);       // 128KB
    ushort_t* w2pk  = wpk;
    ushort_t* kw1pk = wpk + 9216;

    k_phase1<<<876, 256, 0, stream>>>(guide, g_w1, g_w2, k_w1, p_w, feat,
                                      x1, fs, wpk, partA);
    k_conv2<<<512, 256, 0, stream>>>(x1, partA, g_g1, g_b1, w2pk, x2, partB);
    k_tail<<<1024, 256, 0, stream>>>(x2, partB, g_g2, g_b2, fs, kw1pk,
                                     k_w2, k_b2, feat, out);
}